// Round 12
// baseline (69.519 us; speedup 1.0000x reference)
//
#include <hip/hip_runtime.h>
#include <hip/hip_bf16.h>

// SimCLR NT-Xent loss v12: symmetric halving — sim=R R^T computed only for
// upper-triangle 128x128 block pairs (br<=bc, 528 blocks); each tile yields
// row-stats (rows of br) AND transposed col-stats (rows of bc). R9's proven
// 2-phase schedule + coalesced swizzled staging kept. Slot-validity scheme
// avoids any init kernel.

#define NROWS 4096
#define DDIM  512
#define NSLOT 128                // 32 other-blocks x 4 waves
#define NT 4                     // 4 tiles of 32 cols per block
#define NEG_BIG (-3.0e38f)
#define SQRT_CSCALE 3.798282562f // sqrt(10*log2(e)); (cA)(cB) = 10*log2(e)*sim
#define LN2 0.69314718055994530942f
#define THR 40.0f                // defer-max threshold (log2 units)

typedef __bf16 bf16x8 __attribute__((ext_vector_type(8)));
typedef float  f32x4  __attribute__((ext_vector_type(4)));

#define GLOAD_LDS16(g, l) __builtin_amdgcn_global_load_lds(                    \
    (const __attribute__((address_space(1))) void*)(g),                        \
    (__attribute__((address_space(3))) void*)(l), 16, 0, 0)

#define MFMA16(a, b, c) __builtin_amdgcn_mfma_f32_16x16x32_bf16((a), (b), (c), 0, 0, 0)

// ---------------- kernel 0: fp32 -> bf16, scaled by sqrt(c) ----------------
__global__ void jl_cvt(const float* __restrict__ in, __bf16* __restrict__ out) {
    int i = (blockIdx.x * 256 + threadIdx.x) * 8;
    float4 a = *(const float4*)(in + i);
    float4 b = *(const float4*)(in + i + 4);
    bf16x8 w;
    w[0] = (__bf16)(a.x * SQRT_CSCALE); w[1] = (__bf16)(a.y * SQRT_CSCALE);
    w[2] = (__bf16)(a.z * SQRT_CSCALE); w[3] = (__bf16)(a.w * SQRT_CSCALE);
    w[4] = (__bf16)(b.x * SQRT_CSCALE); w[5] = (__bf16)(b.y * SQRT_CSCALE);
    w[6] = (__bf16)(b.z * SQRT_CSCALE); w[7] = (__bf16)(b.w * SQRT_CSCALE);
    *(bf16x8*)(out + i) = w;
}

// ---------------- kernel 1: upper-triangle GEMM + row/col LSE partials ----------------
// grid = 528 blocks (pairs br<=bc), 256 threads (4 waves x 32 rows).
__global__ __launch_bounds__(256, 2) void jl_main(const __bf16* __restrict__ rb,
                                                  float* __restrict__ pm,
                                                  float* __restrict__ ps,
                                                  float* __restrict__ pos) {
    __shared__ __align__(16) char smem[2][32][1024];   // 2-slot ring, 64 KB

    // triangular decode: blockIdx -> (br, bc), br <= bc, row-major over bc
    int br = 0, rem = blockIdx.x;
    while (rem >= 32 - br) { rem -= 32 - br; ++br; }
    const int bc = br + rem;

    const int wave = threadIdx.x >> 6;
    const int lane = threadIdx.x & 63;
    const int row0 = br * 128 + wave * 32;   // wave's first row
    const int colb = bc * 128;               // block's first col
    const int lrow = lane & 15;
    const int lk   = lane >> 4;
    const int swz  = (lrow & 7) << 4;
    const char* rbb = (const char*)rb;       // row stride 1024 B

    // A fragments, two 16-row halves: 32 x bf16x8 = 128 VGPR
    bf16x8 afA[16], afB[16];
    {
        const __bf16* arow = rb + (size_t)(row0 + lrow) * DDIM + lk * 8;
        #pragma unroll
        for (int kb = 0; kb < 16; ++kb) {
            afA[kb] = *(const bf16x8*)(arow + kb * 32);
            afB[kb] = *(const bf16x8*)(arow + 16 * DDIM + kb * 32);
        }
    }

    // coalesced swizzled staging: wave w stages rows 8w..8w+7 of the 32-col tile
#define STAGE(J)                                                               \
    do {                                                                       \
        _Pragma("unroll")                                                      \
        for (int j_ = 0; j_ < 8; ++j_) {                                       \
            const int rr_ = wave * 8 + j_;                                     \
            const char* g_ = rbb + (size_t)(colb + (J) * 32 + rr_) * 1024      \
                             + ((lane * 16) ^ ((rr_ & 7) << 4));               \
            GLOAD_LDS16(g_, &smem[(J) & 1][rr_][0]);                           \
        }                                                                      \
    } while (0)

    STAGE(0);

    float m[2][4], s[2][4];
    #pragma unroll
    for (int h = 0; h < 2; ++h)
        #pragma unroll
        for (int r = 0; r < 4; ++r) { m[h][r] = NEG_BIG; s[h][r] = 0.0f; }

    for (int jt = 0; jt < NT; ++jt) {
        asm volatile("s_waitcnt vmcnt(0)" ::: "memory");
        __builtin_amdgcn_s_barrier();
        __builtin_amdgcn_sched_barrier(0);
        if (jt + 1 < NT) STAGE(jt + 1);

        const int cb = jt & 1;
        f32x4 a00 = {0.f,0.f,0.f,0.f}, a01 = {0.f,0.f,0.f,0.f};
        f32x4 a10 = {0.f,0.f,0.f,0.f}, a11 = {0.f,0.f,0.f,0.f};
        __builtin_amdgcn_s_setprio(1);
        #pragma unroll
        for (int kb = 0; kb < 16; ++kb) {
            bf16x8 b0 = *(const bf16x8*)(&smem[cb][lrow][0]      + ((kb * 64 + lk * 16) ^ swz));
            bf16x8 b1 = *(const bf16x8*)(&smem[cb][16 + lrow][0] + ((kb * 64 + lk * 16) ^ swz));
            a00 = MFMA16(afA[kb], b0, a00);
            a10 = MFMA16(afB[kb], b0, a10);
            a01 = MFMA16(afA[kb], b1, a01);
            a11 = MFMA16(afB[kb], b1, a11);
        }
        __builtin_amdgcn_s_setprio(0);

        // y[h][fc]: row = row0 + 16h + 4lk + r,  col = ctile + fc*16 + lrow
        f32x4 y[2][2] = {{a00, a01}, {a10, a11}};
        const int ctile = colb + jt * 32;   // wave-uniform absolute column

        // positive pairs: col = row ^ 2048 lands at fc==h, lrow==4lk+r
        if (ctile == (row0 ^ 2048)) {
            #pragma unroll
            for (int h = 0; h < 2; ++h)
                #pragma unroll
                for (int r = 0; r < 4; ++r)
                    if (lrow == 4 * lk + r) {
                        const int grow = row0 + h * 16 + 4 * lk + r;
                        float v = y[h][h][r];
                        pos[grow] = v;
                        pos[grow ^ 2048] = v;   // mirrored (sim symmetric)
                    }
        }

        // diagonal mask (diag blocks only; NEG_BIG flows through both stats)
        if (br == bc && ctile == row0) {
            #pragma unroll
            for (int h = 0; h < 2; ++h)
                #pragma unroll
                for (int r = 0; r < 4; ++r)
                    if (lrow == 4 * lk + r) y[h][h][r] = NEG_BIG;
        }

        // row-stats: online defer-max update over 16 values
        {
            float t[2][2][4];
            float dmax = NEG_BIG;
            #pragma unroll
            for (int h = 0; h < 2; ++h)
                #pragma unroll
                for (int n = 0; n < 2; ++n)
                    #pragma unroll
                    for (int r = 0; r < 4; ++r) {
                        t[h][n][r] = y[h][n][r] - m[h][r];
                        dmax = fmaxf(dmax, t[h][n][r]);
                    }
            if (__any(dmax > THR)) {
                #pragma unroll
                for (int h = 0; h < 2; ++h)
                    #pragma unroll
                    for (int r = 0; r < 4; ++r) {
                        float y0 = y[h][0][r], y1 = y[h][1][r];
                        float mn = fmaxf(m[h][r], fmaxf(y0, y1));
                        s[h][r] = s[h][r] * __builtin_amdgcn_exp2f(m[h][r] - mn)
                                + __builtin_amdgcn_exp2f(y0 - mn)
                                + __builtin_amdgcn_exp2f(y1 - mn);
                        m[h][r] = mn;
                    }
            } else {
                #pragma unroll
                for (int h = 0; h < 2; ++h)
                    #pragma unroll
                    for (int r = 0; r < 4; ++r)
                        s[h][r] += __builtin_amdgcn_exp2f(t[h][0][r])
                                 + __builtin_amdgcn_exp2f(t[h][1][r]);
            }
        }

        // col-stats (transpose harvest; skip on diag blocks to avoid double count)
        if (br != bc) {
            #pragma unroll
            for (int fc = 0; fc < 2; ++fc) {
                float cm = NEG_BIG;
                #pragma unroll
                for (int h = 0; h < 2; ++h)
                    #pragma unroll
                    for (int r = 0; r < 4; ++r)
                        cm = fmaxf(cm, y[h][fc][r]);
                float cs = 0.0f;
                #pragma unroll
                for (int h = 0; h < 2; ++h)
                    #pragma unroll
                    for (int r = 0; r < 4; ++r)
                        cs += __builtin_amdgcn_exp2f(y[h][fc][r] - cm);
                #pragma unroll
                for (int off = 16; off < 64; off <<= 1) {
                    float mo = __shfl_xor(cm, off, 64);
                    float so = __shfl_xor(cs, off, 64);
                    float mn = fmaxf(cm, mo);
                    cs = cs * __builtin_amdgcn_exp2f(cm - mn)
                       + so * __builtin_amdgcn_exp2f(mo - mn);
                    cm = mn;
                }
                if (lane < 16) {   // lk==0 holds merged stats for col ctile+fc*16+lane
                    const int gcol = ctile + fc * 16 + lane;
                    pm[(size_t)gcol * NSLOT + br * 4 + wave] = cm;
                    ps[(size_t)gcol * NSLOT + br * 4 + wave] = cs;
                }
            }
        }
    }
#undef STAGE

    // end-of-block row-merge across the 16 lanes of each row group
    #pragma unroll
    for (int h = 0; h < 2; ++h)
        #pragma unroll
        for (int r = 0; r < 4; ++r) {
            float mm = m[h][r], ss = s[h][r];
            #pragma unroll
            for (int off = 1; off < 16; off <<= 1) {
                float mo = __shfl_xor(mm, off, 64);
                float so = __shfl_xor(ss, off, 64);
                float mn = fmaxf(mm, mo);
                ss = ss * __builtin_amdgcn_exp2f(mm - mn)
                   + so * __builtin_amdgcn_exp2f(mo - mn);
                mm = mn;
            }
            if (lrow == 0) {
                const int grow = row0 + 16 * h + 4 * lk + r;
                pm[(size_t)grow * NSLOT + bc * 4 + wave] = mm;
                ps[(size_t)grow * NSLOT + bc * 4 + wave] = ss;
            }
        }
}

// ---------------- kernel 2a: per-row loss + per-block partial sum ----------------
// slot (d,w) of row (block bi, wave wi) is valid iff d < bi (col-stats, all w)
// or w == wi (row-stats from tiles (bi, d>=bi)).
__global__ void jl_rowloss(const float* __restrict__ pm, const float* __restrict__ ps,
                           const float* __restrict__ pos, float* __restrict__ part) {
    __shared__ float red[256];
    const int t = threadIdx.x;
    const int row = blockIdx.x * 256 + t;
    const int bi = row >> 7;
    const int wi = (row >> 5) & 3;
    const float* pmr = pm + (size_t)row * NSLOT;
    const float* psr = ps + (size_t)row * NSLOT;

    float mb = NEG_BIG;
    for (int d = 0; d < 32; ++d) {
        if (d < bi) {
            #pragma unroll
            for (int w = 0; w < 4; ++w) mb = fmaxf(mb, pmr[d * 4 + w]);
        } else {
            mb = fmaxf(mb, pmr[d * 4 + wi]);
        }
    }
    float st = 0.0f;
    for (int d = 0; d < 32; ++d) {
        if (d < bi) {
            #pragma unroll
            for (int w = 0; w < 4; ++w)
                st += psr[d * 4 + w] * __builtin_amdgcn_exp2f(pmr[d * 4 + w] - mb);
        } else {
            st += psr[d * 4 + wi] * __builtin_amdgcn_exp2f(pmr[d * 4 + wi] - mb);
        }
    }
    red[t] = mb + __builtin_amdgcn_logf(st) - pos[row];
    __syncthreads();
    for (int off = 128; off > 0; off >>= 1) {
        if (t < off) red[t] += red[t + off];
        __syncthreads();
    }
    if (t == 0) part[blockIdx.x] = red[0];
}

// ---------------- kernel 2b: final reduce ----------------
__global__ void jl_final(const float* __restrict__ part, float* __restrict__ out) {
    const int t = threadIdx.x;
    float v = (t < NROWS / 256) ? part[t] : 0.0f;
    #pragma unroll
    for (int off = 1; off < 16; off <<= 1) v += __shfl_xor(v, off, 64);
    if (t == 0) out[0] = v * (LN2 / (float)NROWS);
}

extern "C" void kernel_launch(void* const* d_in, const int* in_sizes, int n_in,
                              void* d_out, int out_size, void* d_ws, size_t ws_size,
                              hipStream_t stream) {
    const float* rep = (const float*)d_in[0];
    float* out = (float*)d_out;

    __bf16* rbuf = (__bf16*)d_ws;                               // 4 MB
    float*  pm   = (float*)(rbuf + (size_t)NROWS * DDIM);       // 2 MB
    float*  ps   = pm + (size_t)NROWS * NSLOT;                  // 2 MB
    float*  pos  = ps + (size_t)NROWS * NSLOT;                  // 16 KB
    float*  part = pos + NROWS;

    jl_cvt<<<(NROWS * DDIM) / (256 * 8), 256, 0, stream>>>(rep, rbuf);
    jl_main<<<528, 256, 0, stream>>>(rbuf, pm, ps, pos);
    jl_rowloss<<<NROWS / 256, 256, 0, stream>>>(pm, ps, pos, part);
    jl_final<<<1, 64, 0, stream>>>(part, out);
}

// Round 13
// 47.121 us; speedup vs baseline: 1.4753x; 1.4753x over previous
//
#include <hip/hip_runtime.h>
#include <hip/hip_bf16.h>

// SimCLR NT-Xent loss v13: exact R9 core (best measured: 42.0 us) + fused
// single-block rowloss+final reduction (saves one launch + part[] round-trip).
// R9 core: coalesced swizzled B staging (1KB/wave-instr gload_lds), 32-col
// full-K tiles, race-free 2-phase schedule, A resident in 128 VGPRs, (256,2).

#define NROWS 4096
#define DDIM  512
#define NSPLIT 16                // column splits (256 cols each)
#define NT 8                     // 8 tiles of 32 cols per block
#define BM 128                   // rows per block (4 waves x 32)
#define NEG_BIG (-3.0e38f)
#define SQRT_CSCALE 3.798282562f // sqrt(10*log2(e)); (sqrt(c)A)(sqrt(c)B) = c*sim
#define LN2 0.69314718055994530942f
#define THR 40.0f                // defer-max threshold (log2 units)

typedef __bf16 bf16x8 __attribute__((ext_vector_type(8)));
typedef float  f32x4  __attribute__((ext_vector_type(4)));

#define GLOAD_LDS16(g, l) __builtin_amdgcn_global_load_lds(                    \
    (const __attribute__((address_space(1))) void*)(g),                        \
    (__attribute__((address_space(3))) void*)(l), 16, 0, 0)

#define MFMA16(a, b, c) __builtin_amdgcn_mfma_f32_16x16x32_bf16((a), (b), (c), 0, 0, 0)

// ---------------- kernel 0: fp32 -> bf16, scaled by sqrt(c) ----------------
__global__ void jl_cvt(const float* __restrict__ in, __bf16* __restrict__ out) {
    int i = (blockIdx.x * 256 + threadIdx.x) * 8;
    float4 a = *(const float4*)(in + i);
    float4 b = *(const float4*)(in + i + 4);
    bf16x8 w;
    w[0] = (__bf16)(a.x * SQRT_CSCALE); w[1] = (__bf16)(a.y * SQRT_CSCALE);
    w[2] = (__bf16)(a.z * SQRT_CSCALE); w[3] = (__bf16)(a.w * SQRT_CSCALE);
    w[4] = (__bf16)(b.x * SQRT_CSCALE); w[5] = (__bf16)(b.y * SQRT_CSCALE);
    w[6] = (__bf16)(b.z * SQRT_CSCALE); w[7] = (__bf16)(b.w * SQRT_CSCALE);
    *(bf16x8*)(out + i) = w;
}

// ---------------- kernel 1: fused GEMM + log2-sum-exp2 partials (R9 exact) ----------------
// grid = 32 rowblocks x 16 colsplits = 512 blocks (2/CU), 256 threads (4 waves).
// block: rows [rbk*128, +128), cols [q*256, +256) as 8 tiles of 32 cols x K512.
__global__ __launch_bounds__(256, 2) void jl_main(const __bf16* __restrict__ rb,
                                                  float* __restrict__ pm,
                                                  float* __restrict__ ps,
                                                  float* __restrict__ pos) {
    // 2 buffers x 32 rows x 1KB, row-major with XOR-swizzled 16B chunks
    __shared__ __align__(16) char smem[2][32][1024];

    const int rbk  = blockIdx.x >> 4;   // 0..31
    const int q    = blockIdx.x & 15;   // 0..15
    const int wave = threadIdx.x >> 6;
    const int lane = threadIdx.x & 63;

    const int row0 = rbk * BM + wave * 32;   // wave's first row (32 rows)
    const int col0 = q * 256;
    const int lrow = lane & 15;
    const int lk   = lane >> 4;
    const int swz  = (lrow & 7) << 4;        // read-side XOR (byte units)

    // A fragments, two 16-row halves: 32 x bf16x8 = 128 VGPR (needs (256,2))
    bf16x8 afA[16], afB[16];
    {
        const __bf16* arow = rb + (size_t)(row0 + lrow) * DDIM + lk * 8;
        #pragma unroll
        for (int kb = 0; kb < 16; ++kb) {
            afA[kb] = *(const bf16x8*)(arow + kb * 32);
            afB[kb] = *(const bf16x8*)(arow + 16 * DDIM + kb * 32);
        }
    }

    // coalesced B staging: wave w stages rows 8w..8w+7 of the 32-row tile.
    // per-lane global byte = row_base + (lane*16 ^ ((row&7)<<4))  [same XOR as read]
#define STAGE(J)                                                               \
    do {                                                                       \
        _Pragma("unroll")                                                      \
        for (int i_ = 0; i_ < 8; ++i_) {                                       \
            const int rl_ = wave * 8 + i_;                                     \
            const char* g_ = (const char*)(rb + (size_t)(col0 + (J) * 32 + rl_) * DDIM) \
                             + ((lane * 16) ^ ((rl_ & 7) << 4));               \
            GLOAD_LDS16(g_, &smem[(J) & 1][rl_][0]);                           \
        }                                                                      \
    } while (0)

    STAGE(0);

    float m[2][4], s[2][4];
    #pragma unroll
    for (int h = 0; h < 2; ++h)
        #pragma unroll
        for (int r = 0; r < 4; ++r) { m[h][r] = NEG_BIG; s[h][r] = 0.0f; }

    for (int jt = 0; jt < NT; ++jt) {
        // race-free 2-phase: drain own stage loads, sync, then prefetch next
        asm volatile("s_waitcnt vmcnt(0)" ::: "memory");
        __builtin_amdgcn_s_barrier();
        __builtin_amdgcn_sched_barrier(0);
        if (jt + 1 < NT) STAGE(jt + 1);

        const int cb = jt & 1;

        f32x4 a00 = {0.f,0.f,0.f,0.f}, a01 = {0.f,0.f,0.f,0.f};
        f32x4 a10 = {0.f,0.f,0.f,0.f}, a11 = {0.f,0.f,0.f,0.f};
        __builtin_amdgcn_s_setprio(1);
        #pragma unroll
        for (int kb = 0; kb < 16; ++kb) {
            // B[col = n*16+lrow][k = kb*32+lk*8], swizzled
            bf16x8 b0 = *(const bf16x8*)(&smem[cb][lrow][0]      + ((kb * 64 + lk * 16) ^ swz));
            bf16x8 b1 = *(const bf16x8*)(&smem[cb][16 + lrow][0] + ((kb * 64 + lk * 16) ^ swz));
            a00 = MFMA16(afA[kb], b0, a00);
            a10 = MFMA16(afB[kb], b0, a10);
            a01 = MFMA16(afA[kb], b1, a01);
            a11 = MFMA16(afB[kb], b1, a11);
        }
        __builtin_amdgcn_s_setprio(0);

        // y[h][n]: row = row0 + h*16 + 4*lk + r,  col = ctile + n*16 + lrow
        f32x4 y[2][2] = {{a00, a01}, {a10, a11}};
        const int ctile = col0 + jt * 32;   // wave-uniform

        // positive-pair tile (uniform, rare): partner of row i is i^2048
        if (ctile == (row0 ^ 2048)) {
            #pragma unroll
            for (int h = 0; h < 2; ++h)
                #pragma unroll
                for (int r = 0; r < 4; ++r)
                    if (lrow == 4 * lk + r)
                        pos[row0 + h * 16 + 4 * lk + r] = y[h][h][r];
        }

        if (ctile == row0) {
            // diagonal tile (1 per wave): mask col==row then full online update
            #pragma unroll
            for (int h = 0; h < 2; ++h)
                #pragma unroll
                for (int r = 0; r < 4; ++r) {
                    if (lrow == 4 * lk + r) y[h][h][r] = NEG_BIG;
                    float y0 = y[h][0][r], y1 = y[h][1][r];
                    float mn = fmaxf(m[h][r], fmaxf(y0, y1));
                    s[h][r] = s[h][r] * __builtin_amdgcn_exp2f(m[h][r] - mn)
                            + __builtin_amdgcn_exp2f(y0 - mn)
                            + __builtin_amdgcn_exp2f(y1 - mn);
                    m[h][r] = mn;
                }
        } else {
            float t[2][2][4];
            float dmax = NEG_BIG;
            #pragma unroll
            for (int h = 0; h < 2; ++h)
                #pragma unroll
                for (int n = 0; n < 2; ++n)
                    #pragma unroll
                    for (int r = 0; r < 4; ++r) {
                        t[h][n][r] = y[h][n][r] - m[h][r];
                        dmax = fmaxf(dmax, t[h][n][r]);
                    }
            if (__any(dmax > THR)) {
                #pragma unroll
                for (int h = 0; h < 2; ++h)
                    #pragma unroll
                    for (int r = 0; r < 4; ++r) {
                        float y0 = y[h][0][r], y1 = y[h][1][r];
                        float mn = fmaxf(m[h][r], fmaxf(y0, y1));
                        s[h][r] = s[h][r] * __builtin_amdgcn_exp2f(m[h][r] - mn)
                                + __builtin_amdgcn_exp2f(y0 - mn)
                                + __builtin_amdgcn_exp2f(y1 - mn);
                        m[h][r] = mn;
                    }
            } else {
                #pragma unroll
                for (int h = 0; h < 2; ++h)
                    #pragma unroll
                    for (int r = 0; r < 4; ++r)
                        s[h][r] += __builtin_amdgcn_exp2f(t[h][0][r])
                                 + __builtin_amdgcn_exp2f(t[h][1][r]);
            }
        }
    }
#undef STAGE

    // merge (m,s) across the 16 lanes of each row group, write partials
    #pragma unroll
    for (int h = 0; h < 2; ++h)
        #pragma unroll
        for (int r = 0; r < 4; ++r) {
            float mm = m[h][r], ss = s[h][r];
            #pragma unroll
            for (int off = 1; off < 16; off <<= 1) {
                float mo = __shfl_xor(mm, off, 64);
                float so = __shfl_xor(ss, off, 64);
                float mn = fmaxf(mm, mo);
                ss = ss * __builtin_amdgcn_exp2f(mm - mn)
                   + so * __builtin_amdgcn_exp2f(mo - mn);
                mm = mn;
            }
            if (lrow == 0) {
                const int grow = row0 + 16 * h + 4 * lk + r;
                pm[grow * NSPLIT + q] = mm;
                ps[grow * NSPLIT + q] = ss;
            }
        }
}

// ---------------- kernel 2: fused per-row loss + full reduction (1 block) ----------------
__global__ __launch_bounds__(1024) void jl_rowfin(const float* __restrict__ pm,
                                                  const float* __restrict__ ps,
                                                  const float* __restrict__ pos,
                                                  float* __restrict__ out) {
    __shared__ float red[1024];
    const int t = threadIdx.x;
    float acc = 0.0f;
    for (int row = t; row < NROWS; row += 1024) {
        const float* pmr = pm + row * NSPLIT;
        const float* psr = ps + row * NSPLIT;
        float mb = NEG_BIG;
        #pragma unroll
        for (int qq = 0; qq < NSPLIT; ++qq) mb = fmaxf(mb, pmr[qq]);
        float st = 0.0f;
        #pragma unroll
        for (int qq = 0; qq < NSPLIT; ++qq)
            st += psr[qq] * __builtin_amdgcn_exp2f(pmr[qq] - mb);
        acc += mb + __builtin_amdgcn_logf(st) - pos[row];
    }
    red[t] = acc;
    __syncthreads();
    for (int off = 512; off > 0; off >>= 1) {
        if (t < off) red[t] += red[t + off];
        __syncthreads();
    }
    if (t == 0) out[0] = red[0] * (LN2 / (float)NROWS);
}

extern "C" void kernel_launch(void* const* d_in, const int* in_sizes, int n_in,
                              void* d_out, int out_size, void* d_ws, size_t ws_size,
                              hipStream_t stream) {
    const float* rep = (const float*)d_in[0];
    float* out = (float*)d_out;

    __bf16* rbuf = (__bf16*)d_ws;
    float*  pm   = (float*)(rbuf + (size_t)NROWS * DDIM);
    float*  ps   = pm + NROWS * NSPLIT;
    float*  pos  = ps + NROWS * NSPLIT;

    jl_cvt<<<(NROWS * DDIM) / (256 * 8), 256, 0, stream>>>(rep, rbuf);
    jl_main<<<32 * NSPLIT, 256, 0, stream>>>(rbuf, pm, ps, pos);
    jl_rowfin<<<1, 1024, 0, stream>>>(pm, ps, pos, out);
}

// Round 14
// 42.035 us; speedup vs baseline: 1.6538x; 1.1210x over previous
//
#include <hip/hip_runtime.h>
#include <hip/hip_bf16.h>

// SimCLR NT-Xent loss v14: R9 core + T15 deferred epilogue — tile jt-1's LSE
// (VALU/TRANS) runs while tile jt's ds_read+MFMA burst is in flight. Full
// unroll (static prev-state, rule #20), setprio removed (scheduler fence).
// Reduction path reverted to R9's rowloss(16 blocks)+final.

#define NROWS 4096
#define DDIM  512
#define NSPLIT 16                // column splits (256 cols each)
#define NT 8                     // 8 tiles of 32 cols per block
#define BM 128                   // rows per block (4 waves x 32)
#define NEG_BIG (-3.0e38f)
#define SQRT_CSCALE 3.798282562f // sqrt(10*log2(e)); (sqrt(c)A)(sqrt(c)B) = c*sim
#define LN2 0.69314718055994530942f
#define THR 40.0f                // defer-max threshold (log2 units)

typedef __bf16 bf16x8 __attribute__((ext_vector_type(8)));
typedef float  f32x4  __attribute__((ext_vector_type(4)));

#define GLOAD_LDS16(g, l) __builtin_amdgcn_global_load_lds(                    \
    (const __attribute__((address_space(1))) void*)(g),                        \
    (__attribute__((address_space(3))) void*)(l), 16, 0, 0)

#define MFMA16(a, b, c) __builtin_amdgcn_mfma_f32_16x16x32_bf16((a), (b), (c), 0, 0, 0)

// ---------------- kernel 0: fp32 -> bf16, scaled by sqrt(c) ----------------
__global__ void jl_cvt(const float* __restrict__ in, __bf16* __restrict__ out) {
    int i = (blockIdx.x * 256 + threadIdx.x) * 8;
    float4 a = *(const float4*)(in + i);
    float4 b = *(const float4*)(in + i + 4);
    bf16x8 w;
    w[0] = (__bf16)(a.x * SQRT_CSCALE); w[1] = (__bf16)(a.y * SQRT_CSCALE);
    w[2] = (__bf16)(a.z * SQRT_CSCALE); w[3] = (__bf16)(a.w * SQRT_CSCALE);
    w[4] = (__bf16)(b.x * SQRT_CSCALE); w[5] = (__bf16)(b.y * SQRT_CSCALE);
    w[6] = (__bf16)(b.z * SQRT_CSCALE); w[7] = (__bf16)(b.w * SQRT_CSCALE);
    *(bf16x8*)(out + i) = w;
}

// ---------------- kernel 1: fused GEMM + log2-sum-exp2 partials ----------------
// grid = 32 rowblocks x 16 colsplits = 512 blocks (2/CU), 256 threads (4 waves).
// block: rows [rbk*128, +128), cols [q*256, +256) as 8 tiles of 32 cols x K512.
__global__ __launch_bounds__(256, 2) void jl_main(const __bf16* __restrict__ rb,
                                                  float* __restrict__ pm,
                                                  float* __restrict__ ps,
                                                  float* __restrict__ pos) {
    // 2 buffers x 32 rows x 1KB, row-major with XOR-swizzled 16B chunks
    __shared__ __align__(16) char smem[2][32][1024];

    const int rbk  = blockIdx.x >> 4;   // 0..31
    const int q    = blockIdx.x & 15;   // 0..15
    const int wave = threadIdx.x >> 6;
    const int lane = threadIdx.x & 63;

    const int row0 = rbk * BM + wave * 32;   // wave's first row (32 rows)
    const int col0 = q * 256;
    const int lrow = lane & 15;
    const int lk   = lane >> 4;
    const int swz  = (lrow & 7) << 4;        // read-side XOR (byte units)

    // A fragments, two 16-row halves: 32 x bf16x8 = 128 VGPR (needs (256,2))
    bf16x8 afA[16], afB[16];
    {
        const __bf16* arow = rb + (size_t)(row0 + lrow) * DDIM + lk * 8;
        #pragma unroll
        for (int kb = 0; kb < 16; ++kb) {
            afA[kb] = *(const bf16x8*)(arow + kb * 32);
            afB[kb] = *(const bf16x8*)(arow + 16 * DDIM + kb * 32);
        }
    }

    // coalesced B staging: wave w stages rows 8w..8w+7 of the 32-row tile.
#define STAGE(J)                                                               \
    do {                                                                       \
        _Pragma("unroll")                                                      \
        for (int i_ = 0; i_ < 8; ++i_) {                                       \
            const int rl_ = wave * 8 + i_;                                     \
            const char* g_ = (const char*)(rb + (size_t)(col0 + (J) * 32 + rl_) * DDIM) \
                             + ((lane * 16) ^ ((rl_ & 7) << 4));               \
            GLOAD_LDS16(g_, &smem[(J) & 1][rl_][0]);                           \
        }                                                                      \
    } while (0)

    STAGE(0);

    float m[2][4], s[2][4];
    #pragma unroll
    for (int h = 0; h < 2; ++h)
        #pragma unroll
        for (int r = 0; r < 4; ++r) { m[h][r] = NEG_BIG; s[h][r] = 0.0f; }

    // deferred-epilogue state (SSA-static under full unroll)
    f32x4 q00 = {0,0,0,0}, q01 = {0,0,0,0}, q10 = {0,0,0,0}, q11 = {0,0,0,0};

    // epilogue for tile with values v00..v11 at absolute column ct
#define EPILOGUE(v00, v01, v10, v11, ct)                                       \
    do {                                                                       \
        f32x4 y[2][2] = {{(v00), (v01)}, {(v10), (v11)}};                      \
        if ((ct) == (row0 ^ 2048)) {                                           \
            _Pragma("unroll")                                                  \
            for (int h = 0; h < 2; ++h)                                        \
                _Pragma("unroll")                                              \
                for (int r = 0; r < 4; ++r)                                    \
                    if (lrow == 4 * lk + r)                                    \
                        pos[row0 + h * 16 + 4 * lk + r] = y[h][h][r];          \
        }                                                                      \
        if ((ct) == row0) {                                                    \
            _Pragma("unroll")                                                  \
            for (int h = 0; h < 2; ++h)                                        \
                _Pragma("unroll")                                              \
                for (int r = 0; r < 4; ++r) {                                  \
                    if (lrow == 4 * lk + r) y[h][h][r] = NEG_BIG;              \
                    float y0 = y[h][0][r], y1 = y[h][1][r];                    \
                    float mn = fmaxf(m[h][r], fmaxf(y0, y1));                  \
                    s[h][r] = s[h][r] * __builtin_amdgcn_exp2f(m[h][r] - mn)   \
                            + __builtin_amdgcn_exp2f(y0 - mn)                  \
                            + __builtin_amdgcn_exp2f(y1 - mn);                 \
                    m[h][r] = mn;                                              \
                }                                                              \
        } else {                                                               \
            float tv[2][2][4];                                                 \
            float dmax = NEG_BIG;                                              \
            _Pragma("unroll")                                                  \
            for (int h = 0; h < 2; ++h)                                        \
                _Pragma("unroll")                                              \
                for (int n = 0; n < 2; ++n)                                    \
                    _Pragma("unroll")                                          \
                    for (int r = 0; r < 4; ++r) {                              \
                        tv[h][n][r] = y[h][n][r] - m[h][r];                    \
                        dmax = fmaxf(dmax, tv[h][n][r]);                       \
                    }                                                          \
            if (__any(dmax > THR)) {                                           \
                _Pragma("unroll")                                              \
                for (int h = 0; h < 2; ++h)                                    \
                    _Pragma("unroll")                                          \
                    for (int r = 0; r < 4; ++r) {                              \
                        float y0 = y[h][0][r], y1 = y[h][1][r];                \
                        float mn = fmaxf(m[h][r], fmaxf(y0, y1));              \
                        s[h][r] = s[h][r] * __builtin_amdgcn_exp2f(m[h][r] - mn) \
                                + __builtin_amdgcn_exp2f(y0 - mn)              \
                                + __builtin_amdgcn_exp2f(y1 - mn);             \
                        m[h][r] = mn;                                          \
                    }                                                          \
            } else {                                                           \
                _Pragma("unroll")                                              \
                for (int h = 0; h < 2; ++h)                                    \
                    _Pragma("unroll")                                          \
                    for (int r = 0; r < 4; ++r)                                \
                        s[h][r] += __builtin_amdgcn_exp2f(tv[h][0][r])         \
                                 + __builtin_amdgcn_exp2f(tv[h][1][r]);        \
            }                                                                  \
        }                                                                      \
    } while (0)

    #pragma unroll
    for (int jt = 0; jt < NT; ++jt) {
        // race-free 2-phase: drain own stage loads, sync, then prefetch next
        asm volatile("s_waitcnt vmcnt(0)" ::: "memory");
        __builtin_amdgcn_s_barrier();
        __builtin_amdgcn_sched_barrier(0);
        if (jt + 1 < NT) STAGE(jt + 1);

        const int cb = jt & 1;

        f32x4 a00 = {0.f,0.f,0.f,0.f}, a01 = {0.f,0.f,0.f,0.f};
        f32x4 a10 = {0.f,0.f,0.f,0.f}, a11 = {0.f,0.f,0.f,0.f};
        #pragma unroll
        for (int kb = 0; kb < 16; ++kb) {
            bf16x8 b0 = *(const bf16x8*)(&smem[cb][lrow][0]      + ((kb * 64 + lk * 16) ^ swz));
            bf16x8 b1 = *(const bf16x8*)(&smem[cb][16 + lrow][0] + ((kb * 64 + lk * 16) ^ swz));
            a00 = MFMA16(afA[kb], b0, a00);
            a10 = MFMA16(afB[kb], b0, a10);
            a01 = MFMA16(afA[kb], b1, a01);
            a11 = MFMA16(afB[kb], b1, a11);
        }

        // deferred epilogue of tile jt-1: VALU/TRANS overlaps jt's in-flight MFMAs
        if (jt > 0) {
            EPILOGUE(q00, q01, q10, q11, col0 + (jt - 1) * 32);
        }
        q00 = a00; q01 = a01; q10 = a10; q11 = a11;
    }
    // final tile's epilogue
    EPILOGUE(q00, q01, q10, q11, col0 + (NT - 1) * 32);
#undef STAGE
#undef EPILOGUE

    // merge (m,s) across the 16 lanes of each row group, write partials
    #pragma unroll
    for (int h = 0; h < 2; ++h)
        #pragma unroll
        for (int r = 0; r < 4; ++r) {
            float mm = m[h][r], ss = s[h][r];
            #pragma unroll
            for (int off = 1; off < 16; off <<= 1) {
                float mo = __shfl_xor(mm, off, 64);
                float so = __shfl_xor(ss, off, 64);
                float mn = fmaxf(mm, mo);
                ss = ss * __builtin_amdgcn_exp2f(mm - mn)
                   + so * __builtin_amdgcn_exp2f(mo - mn);
                mm = mn;
            }
            if (lrow == 0) {
                const int grow = row0 + 16 * h + 4 * lk + r;
                pm[grow * NSPLIT + q] = mm;
                ps[grow * NSPLIT + q] = ss;
            }
        }
}

// ---------------- kernel 2a: per-row loss + per-block partial sum ----------------
__global__ void jl_rowloss(const float* __restrict__ pm, const float* __restrict__ ps,
                           const float* __restrict__ pos, float* __restrict__ part) {
    __shared__ float red[256];
    const int t = threadIdx.x;
    const int row = blockIdx.x * 256 + t;
    float mb = NEG_BIG;
    #pragma unroll
    for (int qq = 0; qq < NSPLIT; ++qq) mb = fmaxf(mb, pm[row * NSPLIT + qq]);
    float st = 0.0f;
    #pragma unroll
    for (int qq = 0; qq < NSPLIT; ++qq)
        st += ps[row * NSPLIT + qq] * __builtin_amdgcn_exp2f(pm[row * NSPLIT + qq] - mb);
    red[t] = mb + __builtin_amdgcn_logf(st) - pos[row];
    __syncthreads();
    for (int off = 128; off > 0; off >>= 1) {
        if (t < off) red[t] += red[t + off];
        __syncthreads();
    }
    if (t == 0) part[blockIdx.x] = red[0];
}

// ---------------- kernel 2b: final reduce ----------------
__global__ void jl_final(const float* __restrict__ part, float* __restrict__ out) {
    const int t = threadIdx.x;
    float v = (t < NROWS / 256) ? part[t] : 0.0f;
    #pragma unroll
    for (int off = 1; off < 16; off <<= 1) v += __shfl_xor(v, off, 64);
    if (t == 0) out[0] = v * (LN2 / (float)NROWS);
}

extern "C" void kernel_launch(void* const* d_in, const int* in_sizes, int n_in,
                              void* d_out, int out_size, void* d_ws, size_t ws_size,
                              hipStream_t stream) {
    const float* rep = (const float*)d_in[0];
    float* out = (float*)d_out;

    __bf16* rbuf = (__bf16*)d_ws;
    float*  pm   = (float*)(rbuf + (size_t)NROWS * DDIM);
    float*  ps   = pm + NROWS * NSPLIT;
    float*  pos  = ps + NROWS * NSPLIT;
    float*  part = pos + NROWS;

    jl_cvt<<<(NROWS * DDIM) / (256 * 8), 256, 0, stream>>>(rep, rbuf);
    jl_main<<<32 * NSPLIT, 256, 0, stream>>>(rbuf, pm, ps, pos);
    jl_rowloss<<<NROWS / 256, 256, 0, stream>>>(pm, ps, pos, part);
    jl_final<<<1, 64, 0, stream>>>(part, out);
}

// Round 15
// 34.750 us; speedup vs baseline: 2.0005x; 1.2096x over previous
//
#include <hip/hip_runtime.h>
#include <hip/hip_bf16.h>
#include <hip/hip_fp8.h>

// SimCLR NT-Xent loss v15: fp8-e4m3 port of the R9 structure.
// fp8 16x16x32 MFMA = bf16 rate at half the bytes: ds_read/tile halves
// (16x b128), A-frags 64 VGPR -> (256,3) = 3 blocks/CU without spill,
// grid 768 (24 uneven col-splits). Fragment-ordered fp8 buffer from cvt;
// same XOR-swizzled staging/read pair; LSE epilogue identical to R9.

#define NROWS 4096
#define DDIM  512
#define NSPLIT 24                // uneven splits: 16 x 5 tiles + 8 x 6 tiles (128 tiles)
#define BM 128                   // rows per block (4 waves x 32)
#define NEG_BIG (-3.0e38f)
#define SQRT_CSCALE 3.798282562f // sqrt(10*log2(e)); (sqrt(c)A)(sqrt(c)B) = c*sim
#define LN2 0.69314718055994530942f
#define THR 40.0f                // defer-max threshold (log2 units)

typedef float f32x4 __attribute__((ext_vector_type(4)));
typedef long  lx2   __attribute__((ext_vector_type(2)));

#define GLOAD_LDS16(g, l) __builtin_amdgcn_global_load_lds(                    \
    (const __attribute__((address_space(1))) void*)(g),                        \
    (__attribute__((address_space(3))) void*)(l), 16, 0, 0)

#define MFMA8(a, b, c) __builtin_amdgcn_mfma_f32_16x16x32_fp8_fp8((a), (b), (c), 0, 0, 0)

// ---------------- kernel 0: fp32 -> fp8 e4m3, scaled, fragment-ordered ----------------
// out byte for (row, k): row*512 + lk*128 + kb*8 + e, where k = kb*32 + lk*8 + e.
// thread t (0..63 per row) handles k in [8t, 8t+8) = (kb = t>>2, lk = t&3).
__global__ void jl_cvt(const float* __restrict__ in, unsigned char* __restrict__ out) {
    const int i   = blockIdx.x * 256 + threadIdx.x;
    const int row = i >> 6;
    const int t   = i & 63;
    const float* src = in + (size_t)row * DDIM + t * 8;
    float4 x = *(const float4*)(src);
    float4 y = *(const float4*)(src + 4);
    float v[8] = {x.x, x.y, x.z, x.w, y.x, y.y, y.z, y.w};
    unsigned long long pk = 0;
    #pragma unroll
    for (int e = 0; e < 8; ++e) {
        __hip_fp8_e4m3 f(v[e] * SQRT_CSCALE);
        pk |= (unsigned long long)f.__x << (8 * e);
    }
    *(unsigned long long*)(out + (size_t)row * 512 + (t & 3) * 128 + (t >> 2) * 8) = pk;
}

// ---------------- kernel 1: fused fp8 GEMM + log2-sum-exp2 partials ----------------
// grid = 32 rowblocks x 24 colsplits = 768 blocks (3/CU), 256 threads (4 waves).
// split q: tiles [tile0, tile0+NTq) of 32 cols x K512 each.
__global__ __launch_bounds__(256, 3) void jl_main(const unsigned char* __restrict__ rb,
                                                  float* __restrict__ pm,
                                                  float* __restrict__ ps,
                                                  float* __restrict__ pos) {
    // 2 buffers x 32 tile-cols x 512 B (fragment-ordered, XOR-swizzled 16B slots)
    __shared__ __align__(16) char smem[2][32][512];

    const int rbk   = blockIdx.x / NSPLIT;   // 0..31
    const int q     = blockIdx.x % NSPLIT;   // 0..23
    const int tile0 = (q < 16) ? 5 * q : 80 + 6 * (q - 16);
    const int NTq   = (q < 16) ? 5 : 6;

    const int wave = threadIdx.x >> 6;
    const int lane = threadIdx.x & 63;
    const int row0 = rbk * BM + wave * 32;   // wave's first row (32 rows)
    const int lrow = lane & 15;
    const int lk   = lane >> 4;
    const int swz  = (lrow & 7) << 4;        // read-side XOR (byte units)
    const char* rbb = (const char*)rb;       // fp8 row stride 512 B

    // A fragments: 32 longs = 64 VGPR. afA[kb] = A[row0+lrow][k=kb*32+lk*8+..]
    long afA[16], afB[16];
    {
        const char* ar = rbb + (size_t)(row0 + lrow) * 512 + lk * 128;
        #pragma unroll
        for (int j = 0; j < 8; ++j) {
            lx2 v = *(const lx2*)(ar + j * 16);
            lx2 w = *(const lx2*)(ar + 16 * 512 + j * 16);
            afA[2 * j] = v[0]; afA[2 * j + 1] = v[1];
            afB[2 * j] = w[0]; afB[2 * j + 1] = w[1];
        }
    }

    // staging: wave w stages tile-cols [8w, 8w+8) as 4 x 1KB gload_lds (2 cols each).
    // per-lane source: col c = base + (lane>>5), slot s = lane&31,
    // global byte = c*512 + (s*16 ^ ((c&7)<<4))  [inverse of the read swizzle]
#define STAGE(J)                                                               \
    do {                                                                       \
        _Pragma("unroll")                                                      \
        for (int i_ = 0; i_ < 4; ++i_) {                                       \
            const int lc_ = wave * 8 + 2 * i_;            /* local col pair */ \
            const int c_  = (tile0 + (J)) * 32 + lc_ + (lane >> 5);            \
            const char* g_ = rbb + (size_t)c_ * 512                            \
                             + (((lane & 31) * 16) ^ ((c_ & 7) << 4));         \
            GLOAD_LDS16(g_, &smem[(J) & 1][lc_][0]);                           \
        }                                                                      \
    } while (0)

    STAGE(0);

    float m[2][4], s[2][4];
    #pragma unroll
    for (int h = 0; h < 2; ++h)
        #pragma unroll
        for (int r = 0; r < 4; ++r) { m[h][r] = NEG_BIG; s[h][r] = 0.0f; }

    for (int jt = 0; jt < NTq; ++jt) {
        // race-free 2-phase: drain own stage loads, sync, then prefetch next
        asm volatile("s_waitcnt vmcnt(0)" ::: "memory");
        __builtin_amdgcn_s_barrier();
        __builtin_amdgcn_sched_barrier(0);
        if (jt + 1 < NTq) STAGE(jt + 1);

        const int cb = jt & 1;

        f32x4 a00 = {0.f,0.f,0.f,0.f}, a01 = {0.f,0.f,0.f,0.f};
        f32x4 a10 = {0.f,0.f,0.f,0.f}, a11 = {0.f,0.f,0.f,0.f};
        __builtin_amdgcn_s_setprio(1);
        #pragma unroll
        for (int j = 0; j < 8; ++j) {
            // b128 at fragment offset (lk*128 + j*16) ^ swz covers kb=2j, 2j+1
            lx2 b0 = *(const lx2*)(&smem[cb][lrow][0]      + ((lk * 128 + j * 16) ^ swz));
            lx2 b1 = *(const lx2*)(&smem[cb][16 + lrow][0] + ((lk * 128 + j * 16) ^ swz));
            a00 = MFMA8(afA[2 * j],     b0[0], a00);
            a10 = MFMA8(afB[2 * j],     b0[0], a10);
            a01 = MFMA8(afA[2 * j],     b1[0], a01);
            a11 = MFMA8(afB[2 * j],     b1[0], a11);
            a00 = MFMA8(afA[2 * j + 1], b0[1], a00);
            a10 = MFMA8(afB[2 * j + 1], b0[1], a10);
            a01 = MFMA8(afA[2 * j + 1], b1[1], a01);
            a11 = MFMA8(afB[2 * j + 1], b1[1], a11);
        }
        __builtin_amdgcn_s_setprio(0);

        // y[h][n]: row = row0 + h*16 + 4*lk + r,  col = ctile + n*16 + lrow
        f32x4 y[2][2] = {{a00, a01}, {a10, a11}};
        const int ctile = (tile0 + jt) * 32;   // wave-uniform absolute column

        // positive-pair tile (uniform, rare): partner of row i is i^2048
        if (ctile == (row0 ^ 2048)) {
            #pragma unroll
            for (int h = 0; h < 2; ++h)
                #pragma unroll
                for (int r = 0; r < 4; ++r)
                    if (lrow == 4 * lk + r)
                        pos[row0 + h * 16 + 4 * lk + r] = y[h][h][r];
        }

        if (ctile == row0) {
            // diagonal tile (1 per wave): mask col==row then full online update
            #pragma unroll
            for (int h = 0; h < 2; ++h)
                #pragma unroll
                for (int r = 0; r < 4; ++r) {
                    if (lrow == 4 * lk + r) y[h][h][r] = NEG_BIG;
                    float y0 = y[h][0][r], y1 = y[h][1][r];
                    float mn = fmaxf(m[h][r], fmaxf(y0, y1));
                    s[h][r] = s[h][r] * __builtin_amdgcn_exp2f(m[h][r] - mn)
                            + __builtin_amdgcn_exp2f(y0 - mn)
                            + __builtin_amdgcn_exp2f(y1 - mn);
                    m[h][r] = mn;
                }
        } else {
            float t[2][2][4];
            float dmax = NEG_BIG;
            #pragma unroll
            for (int h = 0; h < 2; ++h)
                #pragma unroll
                for (int n = 0; n < 2; ++n)
                    #pragma unroll
                    for (int r = 0; r < 4; ++r) {
                        t[h][n][r] = y[h][n][r] - m[h][r];
                        dmax = fmaxf(dmax, t[h][n][r]);
                    }
            if (__any(dmax > THR)) {
                #pragma unroll
                for (int h = 0; h < 2; ++h)
                    #pragma unroll
                    for (int r = 0; r < 4; ++r) {
                        float y0 = y[h][0][r], y1 = y[h][1][r];
                        float mn = fmaxf(m[h][r], fmaxf(y0, y1));
                        s[h][r] = s[h][r] * __builtin_amdgcn_exp2f(m[h][r] - mn)
                                + __builtin_amdgcn_exp2f(y0 - mn)
                                + __builtin_amdgcn_exp2f(y1 - mn);
                        m[h][r] = mn;
                    }
            } else {
                #pragma unroll
                for (int h = 0; h < 2; ++h)
                    #pragma unroll
                    for (int r = 0; r < 4; ++r)
                        s[h][r] += __builtin_amdgcn_exp2f(t[h][0][r])
                                 + __builtin_amdgcn_exp2f(t[h][1][r]);
            }
        }
    }
#undef STAGE

    // merge (m,s) across the 16 lanes of each row group, write partials
    #pragma unroll
    for (int h = 0; h < 2; ++h)
        #pragma unroll
        for (int r = 0; r < 4; ++r) {
            float mm = m[h][r], ss = s[h][r];
            #pragma unroll
            for (int off = 1; off < 16; off <<= 1) {
                float mo = __shfl_xor(mm, off, 64);
                float so = __shfl_xor(ss, off, 64);
                float mn = fmaxf(mm, mo);
                ss = ss * __builtin_amdgcn_exp2f(mm - mn)
                   + so * __builtin_amdgcn_exp2f(mo - mn);
                mm = mn;
            }
            if (lrow == 0) {
                const int grow = row0 + 16 * h + 4 * lk + r;
                pm[grow * NSPLIT + q] = mm;
                ps[grow * NSPLIT + q] = ss;
            }
        }
}

// ---------------- kernel 2a: per-row loss + per-block partial sum ----------------
__global__ void jl_rowloss(const float* __restrict__ pm, const float* __restrict__ ps,
                           const float* __restrict__ pos, float* __restrict__ part) {
    __shared__ float red[256];
    const int t = threadIdx.x;
    const int row = blockIdx.x * 256 + t;
    float mb = NEG_BIG;
    #pragma unroll
    for (int qq = 0; qq < NSPLIT; ++qq) mb = fmaxf(mb, pm[row * NSPLIT + qq]);
    float st = 0.0f;
    #pragma unroll
    for (int qq = 0; qq < NSPLIT; ++qq)
        st += ps[row * NSPLIT + qq] * __builtin_amdgcn_exp2f(pm[row * NSPLIT + qq] - mb);
    red[t] = mb + __builtin_amdgcn_logf(st) - pos[row];
    __syncthreads();
    for (int off = 128; off > 0; off >>= 1) {
        if (t < off) red[t] += red[t + off];
        __syncthreads();
    }
    if (t == 0) part[blockIdx.x] = red[0];
}

// ---------------- kernel 2b: final reduce ----------------
__global__ void jl_final(const float* __restrict__ part, float* __restrict__ out) {
    const int t = threadIdx.x;
    float v = (t < NROWS / 256) ? part[t] : 0.0f;
    #pragma unroll
    for (int off = 1; off < 16; off <<= 1) v += __shfl_xor(v, off, 64);
    if (t == 0) out[0] = v * (LN2 / (float)NROWS);
}

extern "C" void kernel_launch(void* const* d_in, const int* in_sizes, int n_in,
                              void* d_out, int out_size, void* d_ws, size_t ws_size,
                              hipStream_t stream) {
    const float* rep = (const float*)d_in[0];
    float* out = (float*)d_out;

    unsigned char* rbuf = (unsigned char*)d_ws;                  // 2 MB fp8
    float*  pm   = (float*)(rbuf + (size_t)NROWS * 512);
    float*  ps   = pm + NROWS * NSPLIT;
    float*  pos  = ps + NROWS * NSPLIT;
    float*  part = pos + NROWS;

    jl_cvt<<<(NROWS * 64) / 256, 256, 0, stream>>>(rep, rbuf);
    jl_main<<<32 * NSPLIT, 256, 0, stream>>>(rbuf, pm, ps, pos);
    jl_rowloss<<<NROWS / 256, 256, 0, stream>>>(pm, ps, pos, part);
    jl_final<<<1, 64, 0, stream>>>(part, out);
}